// Round 1
// baseline (628.101 us; speedup 1.0000x reference)
//
#include <hip/hip_runtime.h>

#define DIM 128

// One 64-lane wave per sample. Each lane holds float2 slices of h and of
// rows 0..2 of the per-sample type matrix; 3 butterfly reductions give the
// 3 dot products; only rows 0..2 of Mh are ever used by the reference score.
__global__ __launch_bounds__(256) void ttd_transe_type_kernel(
    const int* __restrict__ sample,        // (B,3) int32
    const float* __restrict__ entity_emb,  // (E,128)
    const float* __restrict__ type_emb,    // (T*R, 128*128)
    const int* __restrict__ node_type,     // (E,)
    float* __restrict__ out,               // (B,)
    int B, int t_len)
{
    const int wave = threadIdx.x >> 6;
    const int lane = threadIdx.x & 63;
    const int b = blockIdx.x * 4 + wave;
    if (b >= B) return;

    const int head = sample[b * 3 + 0];
    const int rel  = sample[b * 3 + 1];
    const int nt   = node_type[head];
    const long long head_idx = (long long)rel * t_len + nt;

    const float2* __restrict__ hptr =
        (const float2*)(entity_emb + (long long)head * DIM);
    const float2* __restrict__ mptr =
        (const float2*)(type_emb + head_idx * (long long)(DIM * DIM));

    // h: 128 floats = 64 lanes x float2 (coalesced 512B)
    const float2 h  = hptr[lane];
    // rows 0,1,2 of M: contiguous first 1536B of the matrix
    const float2 m0 = mptr[lane];
    const float2 m1 = mptr[64 + lane];
    const float2 m2 = mptr[128 + lane];

    float s0 = fmaf(m0.x, h.x, m0.y * h.y);
    float s1 = fmaf(m1.x, h.x, m1.y * h.y);
    float s2 = fmaf(m2.x, h.x, m2.y * h.y);

    // 64-lane butterfly reduction
    #pragma unroll
    for (int off = 32; off >= 1; off >>= 1) {
        s0 += __shfl_xor(s0, off, 64);
        s1 += __shfl_xor(s1, off, 64);
        s2 += __shfl_xor(s2, off, 64);
    }

    if (lane == 0) {
        const float n0 = s0 / fmaxf(fabsf(s0), 1e-12f);
        const float n1 = s1 / fmaxf(fabsf(s1), 1e-12f);
        const float n2 = s2 / fmaxf(fabsf(s2), 1e-12f);
        out[b] = fabsf(n0 + n1 - n2 + 1e-6f);
    }
}

extern "C" void kernel_launch(void* const* d_in, const int* in_sizes, int n_in,
                              void* d_out, int out_size, void* d_ws, size_t ws_size,
                              hipStream_t stream) {
    const int*   sample       = (const int*)d_in[0];
    const float* entity_emb   = (const float*)d_in[1];
    // d_in[2] = relation_emb — unused by the score (only its row-count matters)
    const float* type_emb     = (const float*)d_in[3];
    const int*   node_type    = (const int*)d_in[4];
    float*       out          = (float*)d_out;

    const int B = in_sizes[0] / 3;
    const int relation_rows = in_sizes[2] / DIM;          // R
    const int type_rows     = in_sizes[3] / (DIM * DIM);  // T*R
    const int t_len = type_rows / relation_rows;          // T

    const int blocks = (B + 3) / 4;  // 4 waves (samples) per 256-thread block
    ttd_transe_type_kernel<<<blocks, 256, 0, stream>>>(
        sample, entity_emb, type_emb, node_type, out, B, t_len);
}

// Round 2
// 608.752 us; speedup vs baseline: 1.0318x; 1.0318x over previous
//
#include <hip/hip_runtime.h>

#define DIM 128

// Score uses only rows 0..2 of Mh: 3 length-128 dot products per sample.
// One 64-lane wave per sample:
//   load1 (float4): lanes 0-31 -> M row0, lanes 32-63 -> M row1  (1024B coalesced)
//   load2 (float4): lanes 0-31 -> M row2, lanes 32-63 -> h       (2x512B)
//   shfl_xor(32) exchange so every lane holds its h-chunk, then 5-step
//   butterfly within each 32-lane half: half0 yields {s0, s2}, half1 {s1, s2}.

__device__ __forceinline__ float dot4(float4 a, float4 b) {
    return fmaf(a.x, b.x, fmaf(a.y, b.y, fmaf(a.z, b.z, a.w * b.w)));
}

__global__ __launch_bounds__(256) void ttd_transe_type_kernel(
    const int* __restrict__ sample,        // (B,3) int32
    const float* __restrict__ entity_emb,  // (E,128)
    const float* __restrict__ type_emb,    // (T*R, 128*128)
    const int* __restrict__ node_type,     // (E,)
    float* __restrict__ out,               // (B,)
    int B, int t_len)
{
    const int lane = threadIdx.x & 63;
    // wave id is uniform per wave -> force SGPR so index chain uses s_loads
    const int wv = __builtin_amdgcn_readfirstlane(threadIdx.x >> 6);
    const int b = blockIdx.x * 4 + wv;
    if (b >= B) return;

    const int head = sample[b * 3 + 0];
    const int rel  = sample[b * 3 + 1];
    const int nt   = node_type[head];
    const long long head_idx = (long long)(rel * t_len + nt);

    const float4* __restrict__ mp =
        (const float4*)(type_emb + head_idx * (long long)(DIM * DIM));
    const float4* __restrict__ hp =
        (const float4*)(entity_emb + (long long)head * DIM);

    const int half = lane >> 5;   // 0: lanes 0-31, 1: lanes 32-63
    const int l5   = lane & 31;

    // load1: rows 0|1 of M (contiguous 1024B across the wave)
    const float4 v1 = mp[lane];                       // half0: m0, half1: m1
    // load2: row2 of M | h
    const float4* p2 = half ? (hp + l5) : (mp + 64 + l5);
    const float4 v2 = *p2;                            // half0: m2, half1: h

    // exchange halves: half0 receives h, half1 receives m2
    float4 v3;
    v3.x = __shfl_xor(v2.x, 32, 64);
    v3.y = __shfl_xor(v2.y, 32, 64);
    v3.z = __shfl_xor(v2.z, 32, 64);
    v3.w = __shfl_xor(v2.w, 32, 64);

    const float4 hv = half ? v2 : v3;   // h chunk, every lane
    const float4 m2 = half ? v3 : v2;   // row2 chunk, every lane

    float pA = dot4(v1, hv);   // half0: partial s0, half1: partial s1
    float pB = dot4(m2, hv);   // partial s2 (both halves)

    #pragma unroll
    for (int off = 16; off >= 1; off >>= 1) {
        pA += __shfl_xor(pA, off, 64);
        pB += __shfl_xor(pB, off, 64);
    }
    // half0 lanes: pA=s0, pB=s2 ; half1 lanes: pA=s1, pB=s2
    const float s1 = __shfl(pA, 32, 64);   // s1 from lane 32

    if (lane == 0) {
        const float s0 = pA, s2 = pB;
        const float n0 = s0 / fmaxf(fabsf(s0), 1e-12f);
        const float n1 = s1 / fmaxf(fabsf(s1), 1e-12f);
        const float n2 = s2 / fmaxf(fabsf(s2), 1e-12f);
        out[b] = fabsf(n0 + n1 - n2 + 1e-6f);
    }
}

extern "C" void kernel_launch(void* const* d_in, const int* in_sizes, int n_in,
                              void* d_out, int out_size, void* d_ws, size_t ws_size,
                              hipStream_t stream) {
    const int*   sample     = (const int*)d_in[0];
    const float* entity_emb = (const float*)d_in[1];
    // d_in[2] = relation_emb — only its row count (R) is needed
    const float* type_emb   = (const float*)d_in[3];
    const int*   node_type  = (const int*)d_in[4];
    float*       out        = (float*)d_out;

    const int B = in_sizes[0] / 3;
    const int relation_rows = in_sizes[2] / DIM;          // R
    const int type_rows     = in_sizes[3] / (DIM * DIM);  // T*R
    const int t_len         = type_rows / relation_rows;  // T

    const int blocks = (B + 3) / 4;  // 4 waves (samples) per 256-thread block
    ttd_transe_type_kernel<<<blocks, 256, 0, stream>>>(
        sample, entity_emb, type_emb, node_type, out, B, t_len);
}